// Round 2
// baseline (681.974 us; speedup 1.0000x reference)
//
#include <hip/hip_runtime.h>

typedef __attribute__((ext_vector_type(8))) short bf16x8;
typedef __attribute__((ext_vector_type(4))) float f32x4;

#define S_LEN 2048
#define NHEAD 16
#define DHEAD 64

__device__ __forceinline__ short f2bf(float f) {
  unsigned u = __builtin_bit_cast(unsigned, f);
  u += 0x7FFFu + ((u >> 16) & 1u);   // round-to-nearest-even
  return (short)(u >> 16);
}

__device__ __forceinline__ unsigned rotl32(unsigned x, int r) {
  return (x << r) | (x >> (32 - r));
}

// ---------------- projection: out[b,h,s,e] = sum_d in[b,s,h,d]*W[e,d] + bias[e]
__global__ __launch_bounds__(256) void proj_kernel(
    const float* __restrict__ qin, const float* __restrict__ kin,
    const float* __restrict__ vin,
    const float* __restrict__ Wq, const float* __restrict__ bq,
    const float* __restrict__ Wk, const float* __restrict__ bk,
    const float* __restrict__ Wv, const float* __restrict__ bv,
    short* __restrict__ Qp, short* __restrict__ Kp, short* __restrict__ Vp)
{
  const int wid = threadIdx.x >> 6;
  const int lane = threadIdx.x & 63;
  const int lr = lane & 15, lg = lane >> 4;
  const int gw = blockIdx.x * 4 + wid;      // 3072 waves total
  const int tensor = gw >> 10;              // 1024 waves per tensor (65536 rows / 64)
  const int rb0 = (gw & 1023) * 64;

  const float* in = tensor == 0 ? qin : (tensor == 1 ? kin : vin);
  const float* W  = tensor == 0 ? Wq  : (tensor == 1 ? Wk  : Wv);
  const float* bb = tensor == 0 ? bq  : (tensor == 1 ? bk  : bv);
  short* op       = tensor == 0 ? Qp  : (tensor == 1 ? Kp  : Vp);

  // B-fragments of W^T: lane holds W[et*16+lr][h*32 + lg*8 + e], contiguous in d
  bf16x8 wf[4][2];
  #pragma unroll
  for (int et = 0; et < 4; ++et)
    #pragma unroll
    for (int h = 0; h < 2; ++h) {
      const float* s = &W[(et*16 + lr)*64 + h*32 + lg*8];
      bf16x8 t;
      #pragma unroll
      for (int e = 0; e < 8; ++e) t[e] = f2bf(s[e]);
      wf[et][h] = t;
    }
  float bias[4];
  #pragma unroll
  for (int et = 0; et < 4; ++et) bias[et] = bb[et*16 + lr];

  for (int blk = 0; blk < 4; ++blk) {
    const int rb = rb0 + blk*16;
    bf16x8 af[2];
    #pragma unroll
    for (int h = 0; h < 2; ++h) {
      const float* s = &in[(size_t)(rb + lr)*64 + h*32 + lg*8];
      bf16x8 t;
      #pragma unroll
      for (int e = 0; e < 8; ++e) t[e] = f2bf(s[e]);
      af[h] = t;
    }
    #pragma unroll
    for (int et = 0; et < 4; ++et) {
      f32x4 acc = {0.f, 0.f, 0.f, 0.f};
      acc = __builtin_amdgcn_mfma_f32_16x16x32_bf16(af[0], wf[et][0], acc, 0, 0, 0);
      acc = __builtin_amdgcn_mfma_f32_16x16x32_bf16(af[1], wf[et][1], acc, 0, 0, 0);
      #pragma unroll
      for (int r = 0; r < 4; ++r) {
        const int row = rb + lg*4 + r;        // flattened (b,s,h)
        const int hh = row & 15;
        const int ss = (row >> 4) & 2047;
        const int bi = row >> 15;
        const size_t orow = ((size_t)(bi*NHEAD + hh))*S_LEN + ss;
        op[orow*64 + et*16 + lr] = f2bf(acc[r] + bias[et]);
      }
    }
  }
}

// ---------------- deterministic dropout keep-bits
// JAX >=0.4.30 threefry_partitionable=True path: per-element counter
// (hi32(idx), lo32(idx)) = (0, idx) since n < 2^32; key (0, 42);
// 32-bit output = out0 ^ out1; uniform = bitcast((bits>>9)|0x3f800000)-1 < 0.9f
#define TF_ROUND4(r0, r1, r2, r3) \
  x0 += x1; x1 = rotl32(x1, r0); x1 ^= x0; \
  x0 += x1; x1 = rotl32(x1, r1); x1 ^= x0; \
  x0 += x1; x1 = rotl32(x1, r2); x1 ^= x0; \
  x0 += x1; x1 = rotl32(x1, r3); x1 ^= x0;

__global__ __launch_bounds__(256) void drop_kernel(unsigned long long* __restrict__ bits)
{
  const unsigned K0 = 0u, K1 = 42u;
  const unsigned K2 = 0x1BD11BDAu ^ K0 ^ K1;
  const unsigned NCH = 2097152u;            // (2*16*2048*2048) / 64 chunks
  const int lane = threadIdx.x & 63;
  const unsigned gw = (blockIdx.x * blockDim.x + threadIdx.x) >> 6;
  const unsigned nw = (gridDim.x * blockDim.x) >> 6;

  for (unsigned c = gw; c < NCH; c += nw) {
    unsigned x0 = K0;                        // hi32(idx) = 0, + K0
    unsigned x1 = c * 64u + (unsigned)lane + K1;   // lo32(idx) + K1
    TF_ROUND4(13,15,26, 6)  x0 += K1; x1 += K2 + 1u;
    TF_ROUND4(17,29,16,24)  x0 += K2; x1 += K0 + 2u;
    TF_ROUND4(13,15,26, 6)  x0 += K0; x1 += K1 + 3u;
    TF_ROUND4(17,29,16,24)  x0 += K1; x1 += K2 + 4u;
    TF_ROUND4(13,15,26, 6)  x0 += K2; x1 += K0 + 5u;
    const unsigned ob = x0 ^ x1;
    const float u = __uint_as_float((ob >> 9) | 0x3f800000u) - 1.0f;
    const unsigned long long b = __ballot(u < 0.9f);
    if (lane == 0) bits[c] = b;
  }
}

// ---------------- flash attention with mask + deterministic dropout
__global__ __launch_bounds__(256) void attn_kernel(
    const short* __restrict__ Qp, const short* __restrict__ Kp,
    const short* __restrict__ Vp, const float* __restrict__ mask,
    const unsigned* __restrict__ kbits, float* __restrict__ out)
{
  __shared__ short Kl[32][72];      // K tile, pad 64->72 (rows 144B, 16B aligned)
  __shared__ short Vt[64][40];      // V tile transposed [d][k], pad 32->40
  __shared__ short Pl[4][16][40];   // per-wave P' 16x32, pad

  const int wid = threadIdx.x >> 6;
  const int lane = threadIdx.x & 63;
  const int lr = lane & 15, lg = lane >> 4;
  const int qblk = blockIdx.x >> 5;   // qblk-major: heads of same qblk adjacent (mask L2 reuse)
  const int bh = blockIdx.x & 31;
  const int b = bh >> 4;
  const int qbase = qblk*64 + wid*16;

  // Q A-fragments: lane holds Q[qbase+lr][h*32 + lg*8 + e]
  bf16x8 qf[2];
  #pragma unroll
  for (int h = 0; h < 2; ++h)
    qf[h] = *(const bf16x8*)&Qp[((size_t)bh*S_LEN + qbase + lr)*64 + h*32 + lg*8];

  f32x4 acc[4];
  #pragma unroll
  for (int dt = 0; dt < 4; ++dt) acc[dt] = (f32x4){0.f,0.f,0.f,0.f};
  float mrow[4] = {-1e30f, -1e30f, -1e30f, -1e30f};
  float lrow[4] = {0.f, 0.f, 0.f, 0.f};

  const float* maskb = mask + (size_t)b * S_LEN * S_LEN;
  const unsigned* bitsb = kbits + (size_t)bh * S_LEN * 64;   // 64 dwords per q-row

  const int tr = threadIdx.x >> 3;        // staging row 0..31
  const int tc = (threadIdx.x & 7) * 8;   // staging col base

  for (int kt = 0; kt < 64; ++kt) {
    const int kb = kt * 32;
    { // stage K tile and transposed V tile
      const size_t gbase = ((size_t)bh*S_LEN + kb + tr)*64 + tc;
      bf16x8 kv = *(const bf16x8*)&Kp[gbase];
      *(bf16x8*)&Kl[tr][tc] = kv;
      bf16x8 vv = *(const bf16x8*)&Vp[gbase];
      #pragma unroll
      for (int j = 0; j < 8; ++j) Vt[tc + j][tr] = vv[j];
    }
    __syncthreads();

    // QK^T: two 16x16 score tiles (K rows load directly as B-fragments of K^T)
    f32x4 sc[2];
    #pragma unroll
    for (int s2 = 0; s2 < 2; ++s2) {
      bf16x8 kf0 = *(const bf16x8*)&Kl[s2*16 + lr][lg*8];
      bf16x8 kf1 = *(const bf16x8*)&Kl[s2*16 + lr][32 + lg*8];
      f32x4 t = {0.f,0.f,0.f,0.f};
      t = __builtin_amdgcn_mfma_f32_16x16x32_bf16(qf[0], kf0, t, 0, 0, 0);
      t = __builtin_amdgcn_mfma_f32_16x16x32_bf16(qf[1], kf1, t, 0, 0, 0);
      sc[s2] = t;
    }

    // mask values + keep-bit words (one broadcast dword per row covers all 32 k)
    float mk0[4], mk1[4]; unsigned bw[4];
    #pragma unroll
    for (int r = 0; r < 4; ++r) {
      const int qrow = qbase + lg*4 + r;
      bw[r]  = bitsb[(size_t)qrow*64 + kt];
      mk0[r] = maskb[(size_t)qrow*S_LEN + kb + lr];
      mk1[r] = maskb[(size_t)qrow*S_LEN + kb + 16 + lr];
    }

    // online softmax (rows live across lanes 0..15 of each group) + dropout
    #pragma unroll
    for (int r = 0; r < 4; ++r) {
      float x0 = sc[0][r] * 0.125f + mk0[r];
      float x1 = sc[1][r] * 0.125f + mk1[r];
      float tm = fmaxf(x0, x1);
      tm = fmaxf(tm, __shfl_xor(tm, 1));
      tm = fmaxf(tm, __shfl_xor(tm, 2));
      tm = fmaxf(tm, __shfl_xor(tm, 4));
      tm = fmaxf(tm, __shfl_xor(tm, 8));
      const float mnew = fmaxf(mrow[r], tm);
      const float corr = __expf(mrow[r] - mnew);
      mrow[r] = mnew;
      const float p0 = __expf(x0 - mnew);
      const float p1 = __expf(x1 - mnew);
      float rs = p0 + p1;
      rs += __shfl_xor(rs, 1);
      rs += __shfl_xor(rs, 2);
      rs += __shfl_xor(rs, 4);
      rs += __shfl_xor(rs, 8);
      lrow[r] = lrow[r] * corr + rs;     // denominator: UNdropped probs
      #pragma unroll
      for (int dt = 0; dt < 4; ++dt) acc[dt][r] *= corr;
      const float d0 = ((bw[r] >> lr) & 1u) ? p0 * (1.0f/0.9f) : 0.0f;
      const float d1 = ((bw[r] >> (lr + 16)) & 1u) ? p1 * (1.0f/0.9f) : 0.0f;
      Pl[wid][lg*4 + r][lr]      = f2bf(d0);
      Pl[wid][lg*4 + r][16 + lr] = f2bf(d1);
    }
    __syncthreads();   // P' cross-lane visibility before A-fragment reads

    // PV: A = P' (16x32) from per-wave LDS, B = V via transposed tile
    bf16x8 pf = *(const bf16x8*)&Pl[wid][lr][lg*8];
    #pragma unroll
    for (int dt = 0; dt < 4; ++dt) {
      bf16x8 vf = *(const bf16x8*)&Vt[dt*16 + lr][lg*8];
      acc[dt] = __builtin_amdgcn_mfma_f32_16x16x32_bf16(pf, vf, acc[dt], 0, 0, 0);
    }
    __syncthreads();   // before next-iter staging overwrites Kl/Vt
  }

  #pragma unroll
  for (int r = 0; r < 4; ++r) {
    const int qrow = qbase + lg*4 + r;
    const float inv = 1.0f / lrow[r];
    #pragma unroll
    for (int dt = 0; dt < 4; ++dt)
      out[((size_t)bh*S_LEN + qrow)*64 + dt*16 + lr] = acc[dt][r] * inv;
  }
}

extern "C" void kernel_launch(void* const* d_in, const int* in_sizes, int n_in,
                              void* d_out, int out_size, void* d_ws, size_t ws_size,
                              hipStream_t stream) {
  const float* qin  = (const float*)d_in[0];
  const float* kin  = (const float*)d_in[1];
  const float* vin  = (const float*)d_in[2];
  const float* mask = (const float*)d_in[3];
  const float* Wq = (const float*)d_in[4];
  const float* bq = (const float*)d_in[5];
  const float* Wk = (const float*)d_in[6];
  const float* bk = (const float*)d_in[7];
  const float* Wv = (const float*)d_in[8];
  const float* bv = (const float*)d_in[9];
  float* out = (float*)d_out;

  // ws layout: Qp/Kp/Vp bf16 [32][2048][64] (8 MiB each), then keep-bits (16 MiB)
  short* Qp = (short*)d_ws;
  short* Kp = Qp + 4194304;
  short* Vp = Kp + 4194304;
  unsigned long long* bits = (unsigned long long*)((char*)d_ws + 25165824);

  hipLaunchKernelGGL(proj_kernel, dim3(768), dim3(256), 0, stream,
                     qin, kin, vin, Wq, bq, Wk, bk, Wv, bv, Qp, Kp, Vp);
  hipLaunchKernelGGL(drop_kernel, dim3(2048), dim3(256), 0, stream, bits);
  hipLaunchKernelGGL(attn_kernel, dim3(1024), dim3(256), 0, stream,
                     Qp, Kp, Vp, mask, (const unsigned*)bits, out);
}

// Round 3
// 666.284 us; speedup vs baseline: 1.0235x; 1.0235x over previous
//
#include <hip/hip_runtime.h>

typedef __attribute__((ext_vector_type(8))) short bf16x8;
typedef __attribute__((ext_vector_type(4))) float f32x4;

#define S_LEN 2048
#define NHEAD 16
#define DHEAD 64

__device__ __forceinline__ short f2bf(float f) {
  unsigned u = __builtin_bit_cast(unsigned, f);
  u += 0x7FFFu + ((u >> 16) & 1u);   // round-to-nearest-even
  return (short)(u >> 16);
}

// ---------------- projection: out[b,h,s,e] = sum_d in[b,s,h,d]*W[e,d] + bias[e]
__global__ __launch_bounds__(256) void proj_kernel(
    const float* __restrict__ qin, const float* __restrict__ kin,
    const float* __restrict__ vin,
    const float* __restrict__ Wq, const float* __restrict__ bq,
    const float* __restrict__ Wk, const float* __restrict__ bk,
    const float* __restrict__ Wv, const float* __restrict__ bv,
    short* __restrict__ Qp, short* __restrict__ Kp, short* __restrict__ Vp)
{
  const int wid = threadIdx.x >> 6;
  const int lane = threadIdx.x & 63;
  const int lr = lane & 15, lg = lane >> 4;
  const int gw = blockIdx.x * 4 + wid;      // 3072 waves total
  const int tensor = gw >> 10;              // 1024 waves per tensor (65536 rows / 64)
  const int rb0 = (gw & 1023) * 64;

  const float* in = tensor == 0 ? qin : (tensor == 1 ? kin : vin);
  const float* W  = tensor == 0 ? Wq  : (tensor == 1 ? Wk  : Wv);
  const float* bb = tensor == 0 ? bq  : (tensor == 1 ? bk  : bv);
  short* op       = tensor == 0 ? Qp  : (tensor == 1 ? Kp  : Vp);

  // B-fragments of W^T: lane holds W[et*16+lr][h*32 + lg*8 + e], contiguous in d
  bf16x8 wf[4][2];
  #pragma unroll
  for (int et = 0; et < 4; ++et)
    #pragma unroll
    for (int h = 0; h < 2; ++h) {
      const float* s = &W[(et*16 + lr)*64 + h*32 + lg*8];
      bf16x8 t;
      #pragma unroll
      for (int e = 0; e < 8; ++e) t[e] = f2bf(s[e]);
      wf[et][h] = t;
    }
  float bias[4];
  #pragma unroll
  for (int et = 0; et < 4; ++et) bias[et] = bb[et*16 + lr];

  for (int blk = 0; blk < 4; ++blk) {
    const int rb = rb0 + blk*16;
    bf16x8 af[2];
    #pragma unroll
    for (int h = 0; h < 2; ++h) {
      const float* s = &in[(size_t)(rb + lr)*64 + h*32 + lg*8];
      bf16x8 t;
      #pragma unroll
      for (int e = 0; e < 8; ++e) t[e] = f2bf(s[e]);
      af[h] = t;
    }
    #pragma unroll
    for (int et = 0; et < 4; ++et) {
      f32x4 acc = {0.f, 0.f, 0.f, 0.f};
      acc = __builtin_amdgcn_mfma_f32_16x16x32_bf16(af[0], wf[et][0], acc, 0, 0, 0);
      acc = __builtin_amdgcn_mfma_f32_16x16x32_bf16(af[1], wf[et][1], acc, 0, 0, 0);
      #pragma unroll
      for (int r = 0; r < 4; ++r) {
        const int row = rb + lg*4 + r;        // flattened (b,s,h)
        const int hh = row & 15;
        const int ss = (row >> 4) & 2047;
        const int bi = row >> 15;
        const size_t orow = ((size_t)(bi*NHEAD + hh))*S_LEN + ss;
        op[orow*64 + et*16 + lr] = f2bf(acc[r] + bias[et]);
      }
    }
  }
}

// ---------------- deterministic dropout keep-bits
// JAX >=0.4.30 threefry_partitionable=True path: per-element counter
// (hi32(idx), lo32(idx)) = (0, idx); key (0, 42); out = out0 ^ out1;
// keep <=> bitcast((out>>9)|0x3f800000)-1 < 0.9f  <=>  out < 7549747u<<9 (exact)
#define TF_R2(r) \
  xa0 += xa1; xb0 += xb1; \
  xa1 = __builtin_amdgcn_alignbit(xa1, xa1, 32 - (r)) ^ xa0; \
  xb1 = __builtin_amdgcn_alignbit(xb1, xb1, 32 - (r)) ^ xb0;

#define TF_G2(r0, r1, r2, r3) TF_R2(r0) TF_R2(r1) TF_R2(r2) TF_R2(r3)

__global__ __launch_bounds__(256) void drop_kernel(unsigned long long* __restrict__ bits)
{
  const unsigned K1 = 42u;
  const unsigned K2 = 0x1BD11BDAu ^ K1;     // K0 = 0
  const unsigned THR = 3865470464u;         // 7549747u << 9
  const unsigned NCH = 2097152u;            // (2*16*2048*2048) / 64 chunks
  const int lane = threadIdx.x & 63;
  const unsigned gw = (blockIdx.x * blockDim.x + threadIdx.x) >> 6;
  const unsigned nw = (gridDim.x * blockDim.x) >> 6;   // 8192 waves
  const unsigned lc = (unsigned)lane + K1;

  for (unsigned c = gw * 2u; c < NCH; c += nw * 2u) {
    // two independent hash chains interleaved for ILP
    unsigned xa0 = 0u, xa1 = c * 64u + lc;
    unsigned xb0 = 0u, xb1 = xa1 + 64u;
    TF_G2(13,15,26, 6)  xa0 += K1; xa1 += K2 + 1u;  xb0 += K1; xb1 += K2 + 1u;
    TF_G2(17,29,16,24)  xa0 += K2; xa1 += 2u;       xb0 += K2; xb1 += 2u;
    TF_G2(13,15,26, 6)               xa1 += K1 + 3u;             xb1 += K1 + 3u;
    TF_G2(17,29,16,24)  xa0 += K1; xa1 += K2 + 4u;  xb0 += K1; xb1 += K2 + 4u;
    TF_G2(13,15,26, 6)  xa0 += K2; xa1 += 5u;       xb0 += K2; xb1 += 5u;
    const unsigned long long ba = __ballot((xa0 ^ xa1) < THR);
    const unsigned long long bb2 = __ballot((xb0 ^ xb1) < THR);
    if (lane == 0) {
      bits[c] = ba;
      bits[c + 1] = bb2;
    }
  }
}

// ---------------- flash attention with mask + deterministic dropout
__global__ __launch_bounds__(256) void attn_kernel(
    const short* __restrict__ Qp, const short* __restrict__ Kp,
    const short* __restrict__ Vp, const float* __restrict__ mask,
    const unsigned* __restrict__ kbits, float* __restrict__ out)
{
  __shared__ short Kl[32][72];      // K tile, pad 64->72 (rows 144B, 16B aligned)
  __shared__ short Vt[64][40];      // V tile transposed [d][k], pad 32->40
  __shared__ short Pl[4][16][40];   // per-wave P' 16x32, pad

  const int wid = threadIdx.x >> 6;
  const int lane = threadIdx.x & 63;
  const int lr = lane & 15, lg = lane >> 4;
  const int qblk = blockIdx.x >> 5;   // qblk-major: heads of same qblk adjacent (mask L2 reuse)
  const int bh = blockIdx.x & 31;
  const int b = bh >> 4;
  const int qbase = qblk*64 + wid*16;

  // Q A-fragments: lane holds Q[qbase+lr][h*32 + lg*8 + e]
  bf16x8 qf[2];
  #pragma unroll
  for (int h = 0; h < 2; ++h)
    qf[h] = *(const bf16x8*)&Qp[((size_t)bh*S_LEN + qbase + lr)*64 + h*32 + lg*8];

  f32x4 acc[4];
  #pragma unroll
  for (int dt = 0; dt < 4; ++dt) acc[dt] = (f32x4){0.f,0.f,0.f,0.f};
  float mrow[4] = {-1e30f, -1e30f, -1e30f, -1e30f};
  float lrow[4] = {0.f, 0.f, 0.f, 0.f};

  const float* maskb = mask + (size_t)b * S_LEN * S_LEN;
  const unsigned* bitsb = kbits + (size_t)bh * S_LEN * 64;   // 64 dwords per q-row

  const int tr = threadIdx.x >> 3;        // staging row 0..31
  const int tc = (threadIdx.x & 7) * 8;   // staging col base

  for (int kt = 0; kt < 64; ++kt) {
    const int kb = kt * 32;
    { // stage K tile and transposed V tile
      const size_t gbase = ((size_t)bh*S_LEN + kb + tr)*64 + tc;
      bf16x8 kv = *(const bf16x8*)&Kp[gbase];
      *(bf16x8*)&Kl[tr][tc] = kv;
      bf16x8 vv = *(const bf16x8*)&Vp[gbase];
      #pragma unroll
      for (int j = 0; j < 8; ++j) Vt[tc + j][tr] = vv[j];
    }
    __syncthreads();

    // QK^T: two 16x16 score tiles (K rows load directly as B-fragments of K^T)
    f32x4 sc[2];
    #pragma unroll
    for (int s2 = 0; s2 < 2; ++s2) {
      bf16x8 kf0 = *(const bf16x8*)&Kl[s2*16 + lr][lg*8];
      bf16x8 kf1 = *(const bf16x8*)&Kl[s2*16 + lr][32 + lg*8];
      f32x4 t = {0.f,0.f,0.f,0.f};
      t = __builtin_amdgcn_mfma_f32_16x16x32_bf16(qf[0], kf0, t, 0, 0, 0);
      t = __builtin_amdgcn_mfma_f32_16x16x32_bf16(qf[1], kf1, t, 0, 0, 0);
      sc[s2] = t;
    }

    // mask values + keep-bit words (one broadcast dword per row covers all 32 k)
    float mk0[4], mk1[4]; unsigned bw[4];
    #pragma unroll
    for (int r = 0; r < 4; ++r) {
      const int qrow = qbase + lg*4 + r;
      bw[r]  = bitsb[(size_t)qrow*64 + kt];
      mk0[r] = maskb[(size_t)qrow*S_LEN + kb + lr];
      mk1[r] = maskb[(size_t)qrow*S_LEN + kb + 16 + lr];
    }

    // online softmax (rows live across lanes 0..15 of each group) + dropout
    #pragma unroll
    for (int r = 0; r < 4; ++r) {
      float x0 = sc[0][r] * 0.125f + mk0[r];
      float x1 = sc[1][r] * 0.125f + mk1[r];
      float tm = fmaxf(x0, x1);
      tm = fmaxf(tm, __shfl_xor(tm, 1));
      tm = fmaxf(tm, __shfl_xor(tm, 2));
      tm = fmaxf(tm, __shfl_xor(tm, 4));
      tm = fmaxf(tm, __shfl_xor(tm, 8));
      const float mnew = fmaxf(mrow[r], tm);
      const float corr = __expf(mrow[r] - mnew);
      mrow[r] = mnew;
      const float p0 = __expf(x0 - mnew);
      const float p1 = __expf(x1 - mnew);
      float rs = p0 + p1;
      rs += __shfl_xor(rs, 1);
      rs += __shfl_xor(rs, 2);
      rs += __shfl_xor(rs, 4);
      rs += __shfl_xor(rs, 8);
      lrow[r] = lrow[r] * corr + rs;     // denominator: UNdropped probs
      #pragma unroll
      for (int dt = 0; dt < 4; ++dt) acc[dt][r] *= corr;
      const float d0 = ((bw[r] >> lr) & 1u) ? p0 * (1.0f/0.9f) : 0.0f;
      const float d1 = ((bw[r] >> (lr + 16)) & 1u) ? p1 * (1.0f/0.9f) : 0.0f;
      Pl[wid][lg*4 + r][lr]      = f2bf(d0);
      Pl[wid][lg*4 + r][16 + lr] = f2bf(d1);
    }
    __syncthreads();   // P' cross-lane visibility before A-fragment reads

    // PV: A = P' (16x32) from per-wave LDS, B = V via transposed tile
    bf16x8 pf = *(const bf16x8*)&Pl[wid][lr][lg*8];
    #pragma unroll
    for (int dt = 0; dt < 4; ++dt) {
      bf16x8 vf = *(const bf16x8*)&Vt[dt*16 + lr][lg*8];
      acc[dt] = __builtin_amdgcn_mfma_f32_16x16x32_bf16(pf, vf, acc[dt], 0, 0, 0);
    }
    __syncthreads();   // before next-iter staging overwrites Kl/Vt
  }

  #pragma unroll
  for (int r = 0; r < 4; ++r) {
    const int qrow = qbase + lg*4 + r;
    const float inv = 1.0f / lrow[r];
    #pragma unroll
    for (int dt = 0; dt < 4; ++dt)
      out[((size_t)bh*S_LEN + qrow)*64 + dt*16 + lr] = acc[dt][r] * inv;
  }
}

extern "C" void kernel_launch(void* const* d_in, const int* in_sizes, int n_in,
                              void* d_out, int out_size, void* d_ws, size_t ws_size,
                              hipStream_t stream) {
  const float* qin  = (const float*)d_in[0];
  const float* kin  = (const float*)d_in[1];
  const float* vin  = (const float*)d_in[2];
  const float* mask = (const float*)d_in[3];
  const float* Wq = (const float*)d_in[4];
  const float* bq = (const float*)d_in[5];
  const float* Wk = (const float*)d_in[6];
  const float* bk = (const float*)d_in[7];
  const float* Wv = (const float*)d_in[8];
  const float* bv = (const float*)d_in[9];
  float* out = (float*)d_out;

  // ws layout: Qp/Kp/Vp bf16 [32][2048][64] (8 MiB each), then keep-bits (16 MiB)
  short* Qp = (short*)d_ws;
  short* Kp = Qp + 4194304;
  short* Vp = Kp + 4194304;
  unsigned long long* bits = (unsigned long long*)((char*)d_ws + 25165824);

  hipLaunchKernelGGL(proj_kernel, dim3(768), dim3(256), 0, stream,
                     qin, kin, vin, Wq, bq, Wk, bk, Wv, bv, Qp, Kp, Vp);
  hipLaunchKernelGGL(drop_kernel, dim3(2048), dim3(256), 0, stream, bits);
  hipLaunchKernelGGL(attn_kernel, dim3(1024), dim3(256), 0, stream,
                     Qp, Kp, Vp, mask, (const unsigned*)bits, out);
}

// Round 4
// 573.363 us; speedup vs baseline: 1.1894x; 1.1621x over previous
//
#include <hip/hip_runtime.h>

typedef __attribute__((ext_vector_type(8))) short bf16x8;
typedef __attribute__((ext_vector_type(4))) float f32x4;

#define S_LEN 2048
#define NHEAD 16
#define DHEAD 64

__device__ __forceinline__ short f2bf(float f) {
  unsigned u = __builtin_bit_cast(unsigned, f);
  u += 0x7FFFu + ((u >> 16) & 1u);   // round-to-nearest-even
  return (short)(u >> 16);
}

// ---------------- projection: out[b,h,s,e] = sum_d in[b,s,h,d]*W[e,d] + bias[e]
__global__ __launch_bounds__(256) void proj_kernel(
    const float* __restrict__ qin, const float* __restrict__ kin,
    const float* __restrict__ vin,
    const float* __restrict__ Wq, const float* __restrict__ bq,
    const float* __restrict__ Wk, const float* __restrict__ bk,
    const float* __restrict__ Wv, const float* __restrict__ bv,
    short* __restrict__ Qp, short* __restrict__ Kp, short* __restrict__ Vp)
{
  const int wid = threadIdx.x >> 6;
  const int lane = threadIdx.x & 63;
  const int lr = lane & 15, lg = lane >> 4;
  const int gw = blockIdx.x * 4 + wid;      // 3072 waves total
  const int tensor = gw >> 10;              // 1024 waves per tensor (65536 rows / 64)
  const int rb0 = (gw & 1023) * 64;

  const float* in = tensor == 0 ? qin : (tensor == 1 ? kin : vin);
  const float* W  = tensor == 0 ? Wq  : (tensor == 1 ? Wk  : Wv);
  const float* bb = tensor == 0 ? bq  : (tensor == 1 ? bk  : bv);
  short* op       = tensor == 0 ? Qp  : (tensor == 1 ? Kp  : Vp);

  // B-fragments of W^T: lane holds W[et*16+lr][h*32 + lg*8 + e], contiguous in d
  bf16x8 wf[4][2];
  #pragma unroll
  for (int et = 0; et < 4; ++et)
    #pragma unroll
    for (int h = 0; h < 2; ++h) {
      const float* s = &W[(et*16 + lr)*64 + h*32 + lg*8];
      bf16x8 t;
      #pragma unroll
      for (int e = 0; e < 8; ++e) t[e] = f2bf(s[e]);
      wf[et][h] = t;
    }
  float bias[4];
  #pragma unroll
  for (int et = 0; et < 4; ++et) bias[et] = bb[et*16 + lr];

  for (int blk = 0; blk < 4; ++blk) {
    const int rb = rb0 + blk*16;
    bf16x8 af[2];
    #pragma unroll
    for (int h = 0; h < 2; ++h) {
      const float* s = &in[(size_t)(rb + lr)*64 + h*32 + lg*8];
      bf16x8 t;
      #pragma unroll
      for (int e = 0; e < 8; ++e) t[e] = f2bf(s[e]);
      af[h] = t;
    }
    #pragma unroll
    for (int et = 0; et < 4; ++et) {
      f32x4 acc = {0.f, 0.f, 0.f, 0.f};
      acc = __builtin_amdgcn_mfma_f32_16x16x32_bf16(af[0], wf[et][0], acc, 0, 0, 0);
      acc = __builtin_amdgcn_mfma_f32_16x16x32_bf16(af[1], wf[et][1], acc, 0, 0, 0);
      #pragma unroll
      for (int r = 0; r < 4; ++r) {
        const int row = rb + lg*4 + r;        // flattened (b,s,h)
        const int hh = row & 15;
        const int ss = (row >> 4) & 2047;
        const int bi = row >> 15;
        const size_t orow = ((size_t)(bi*NHEAD + hh))*S_LEN + ss;
        op[orow*64 + et*16 + lr] = f2bf(acc[r] + bias[et]);
      }
    }
  }
}

// ---------------- threefry2x32-20, key (0,42), counter (0, idx), out = x0^x1
// keep <=> bitcast((out>>9)|0x3f800000)-1 < 0.9f  <=>  out < (7549747u<<9)
// Two independent chains (a,b) interleaved for ILP.
#define TF_R2(r) \
  xa0 += xa1; xb0 += xb1; \
  xa1 = __builtin_amdgcn_alignbit(xa1, xa1, 32 - (r)) ^ xa0; \
  xb1 = __builtin_amdgcn_alignbit(xb1, xb1, 32 - (r)) ^ xb0;

#define TF_G2(r0, r1, r2, r3) TF_R2(r0) TF_R2(r1) TF_R2(r2) TF_R2(r3)

#define TF_K1 42u
#define TF_K2 (0x1BD11BDAu ^ 42u)
#define TF_THR 3865470464u   // 7549747u << 9

// full 20-round hash of (idx) and (idx+16); sets keep0, keep1
#define TF_HASH2(idx, keep0, keep1) { \
  unsigned xa0 = 0u, xa1 = (idx) + TF_K1; \
  unsigned xb0 = 0u, xb1 = (idx) + 16u + TF_K1; \
  TF_G2(13,15,26, 6)  xa0 += TF_K1; xa1 += TF_K2 + 1u;  xb0 += TF_K1; xb1 += TF_K2 + 1u; \
  TF_G2(17,29,16,24)  xa0 += TF_K2; xa1 += 2u;          xb0 += TF_K2; xb1 += 2u; \
  TF_G2(13,15,26, 6)                xa1 += TF_K1 + 3u;                xb1 += TF_K1 + 3u; \
  TF_G2(17,29,16,24)  xa0 += TF_K1; xa1 += TF_K2 + 4u;  xb0 += TF_K1; xb1 += TF_K2 + 4u; \
  TF_G2(13,15,26, 6)  xa0 += TF_K2; xa1 += 5u;          xb0 += TF_K2; xb1 += 5u; \
  keep0 = (xa0 ^ xa1) < TF_THR; \
  keep1 = (xb0 ^ xb1) < TF_THR; \
}

// ---------------- flash attention with mask + fused deterministic dropout
__global__ __launch_bounds__(256) void attn_kernel(
    const short* __restrict__ Qp, const short* __restrict__ Kp,
    const short* __restrict__ Vp, const float* __restrict__ mask,
    float* __restrict__ out)
{
  __shared__ short Kl[32][72];      // K tile, pad 64->72 (rows 144B, 16B aligned)
  __shared__ short Vt[64][40];      // V tile transposed [d][k], pad 32->40
  __shared__ short Pl[4][16][40];   // per-wave P' 16x32, pad

  const int wid = threadIdx.x >> 6;
  const int lane = threadIdx.x & 63;
  const int lr = lane & 15, lg = lane >> 4;
  const int qblk = blockIdx.x >> 5;   // qblk-major: heads of same qblk adjacent (mask L2 reuse)
  const int bh = blockIdx.x & 31;
  const int b = bh >> 4;
  const int qbase = qblk*64 + wid*16;

  // Q A-fragments: lane holds Q[qbase+lr][h*32 + lg*8 + e]
  bf16x8 qf[2];
  #pragma unroll
  for (int h = 0; h < 2; ++h)
    qf[h] = *(const bf16x8*)&Qp[((size_t)bh*S_LEN + qbase + lr)*64 + h*32 + lg*8];

  f32x4 acc[4];
  #pragma unroll
  for (int dt = 0; dt < 4; ++dt) acc[dt] = (f32x4){0.f,0.f,0.f,0.f};
  float mrow[4] = {-1e30f, -1e30f, -1e30f, -1e30f};
  float lrow[4] = {0.f, 0.f, 0.f, 0.f};

  const float* maskb = mask + (size_t)b * S_LEN * S_LEN;
  // per-lane dropout element index base for r=0 row: ((bh*S + qrow)*S) + lr
  const unsigned idxb = (((unsigned)(bh*S_LEN + qbase + lg*4)) << 11) + (unsigned)lr;

  const int tr = threadIdx.x >> 3;        // staging row 0..31
  const int tc = (threadIdx.x & 7) * 8;   // staging col base

  for (int kt = 0; kt < 64; ++kt) {
    const int kb = kt * 32;
    { // stage K tile and transposed V tile
      const size_t gbase = ((size_t)bh*S_LEN + kb + tr)*64 + tc;
      bf16x8 kv = *(const bf16x8*)&Kp[gbase];
      *(bf16x8*)&Kl[tr][tc] = kv;
      bf16x8 vv = *(const bf16x8*)&Vp[gbase];
      #pragma unroll
      for (int j = 0; j < 8; ++j) Vt[tc + j][tr] = vv[j];
    }
    __syncthreads();

    // QK^T: two 16x16 score tiles (K rows load directly as B-fragments of K^T)
    f32x4 sc[2];
    #pragma unroll
    for (int s2 = 0; s2 < 2; ++s2) {
      bf16x8 kf0 = *(const bf16x8*)&Kl[s2*16 + lr][lg*8];
      bf16x8 kf1 = *(const bf16x8*)&Kl[s2*16 + lr][32 + lg*8];
      f32x4 t = {0.f,0.f,0.f,0.f};
      t = __builtin_amdgcn_mfma_f32_16x16x32_bf16(qf[0], kf0, t, 0, 0, 0);
      t = __builtin_amdgcn_mfma_f32_16x16x32_bf16(qf[1], kf1, t, 0, 0, 0);
      sc[s2] = t;
    }

    // mask values (per-row dwords; same dword broadcast across the 16-lane group)
    float mk0[4], mk1[4];
    #pragma unroll
    for (int r = 0; r < 4; ++r) {
      const int qrow = qbase + lg*4 + r;
      mk0[r] = maskb[(size_t)qrow*S_LEN + kb + lr];
      mk1[r] = maskb[(size_t)qrow*S_LEN + kb + 16 + lr];
    }

    // online softmax + fused per-lane threefry dropout
    #pragma unroll
    for (int r = 0; r < 4; ++r) {
      // keep-bits for (qrow, kb+lr) and (qrow, kb+16+lr): hash its own indices
      bool keep0, keep1;
      TF_HASH2(idxb + ((unsigned)r << 11) + (unsigned)kb, keep0, keep1);

      float x0 = sc[0][r] * 0.125f + mk0[r];
      float x1 = sc[1][r] * 0.125f + mk1[r];
      float tm = fmaxf(x0, x1);
      tm = fmaxf(tm, __shfl_xor(tm, 1));
      tm = fmaxf(tm, __shfl_xor(tm, 2));
      tm = fmaxf(tm, __shfl_xor(tm, 4));
      tm = fmaxf(tm, __shfl_xor(tm, 8));
      const float mnew = fmaxf(mrow[r], tm);
      const float corr = __expf(mrow[r] - mnew);
      mrow[r] = mnew;
      const float p0 = __expf(x0 - mnew);
      const float p1 = __expf(x1 - mnew);
      float rs = p0 + p1;
      rs += __shfl_xor(rs, 1);
      rs += __shfl_xor(rs, 2);
      rs += __shfl_xor(rs, 4);
      rs += __shfl_xor(rs, 8);
      lrow[r] = lrow[r] * corr + rs;     // denominator: UNdropped probs
      #pragma unroll
      for (int dt = 0; dt < 4; ++dt) acc[dt][r] *= corr;
      const float d0 = keep0 ? p0 * (1.0f/0.9f) : 0.0f;
      const float d1 = keep1 ? p1 * (1.0f/0.9f) : 0.0f;
      Pl[wid][lg*4 + r][lr]      = f2bf(d0);
      Pl[wid][lg*4 + r][16 + lr] = f2bf(d1);
    }
    __syncthreads();   // P' cross-lane visibility before A-fragment reads

    // PV: A = P' (16x32) from per-wave LDS, B = V via transposed tile
    bf16x8 pf = *(const bf16x8*)&Pl[wid][lr][lg*8];
    #pragma unroll
    for (int dt = 0; dt < 4; ++dt) {
      bf16x8 vf = *(const bf16x8*)&Vt[dt*16 + lr][lg*8];
      acc[dt] = __builtin_amdgcn_mfma_f32_16x16x32_bf16(pf, vf, acc[dt], 0, 0, 0);
    }
    __syncthreads();   // before next-iter staging overwrites Kl/Vt
  }

  #pragma unroll
  for (int r = 0; r < 4; ++r) {
    const int qrow = qbase + lg*4 + r;
    const float inv = 1.0f / lrow[r];
    #pragma unroll
    for (int dt = 0; dt < 4; ++dt)
      out[((size_t)bh*S_LEN + qrow)*64 + dt*16 + lr] = acc[dt][r] * inv;
  }
}

extern "C" void kernel_launch(void* const* d_in, const int* in_sizes, int n_in,
                              void* d_out, int out_size, void* d_ws, size_t ws_size,
                              hipStream_t stream) {
  const float* qin  = (const float*)d_in[0];
  const float* kin  = (const float*)d_in[1];
  const float* vin  = (const float*)d_in[2];
  const float* mask = (const float*)d_in[3];
  const float* Wq = (const float*)d_in[4];
  const float* bq = (const float*)d_in[5];
  const float* Wk = (const float*)d_in[6];
  const float* bk = (const float*)d_in[7];
  const float* Wv = (const float*)d_in[8];
  const float* bv = (const float*)d_in[9];
  float* out = (float*)d_out;

  // ws layout: Qp/Kp/Vp bf16 [32][2048][64] (8 MiB each)
  short* Qp = (short*)d_ws;
  short* Kp = Qp + 4194304;
  short* Vp = Kp + 4194304;

  hipLaunchKernelGGL(proj_kernel, dim3(768), dim3(256), 0, stream,
                     qin, kin, vin, Wq, bq, Wk, bk, Wv, bv, Qp, Kp, Vp);
  hipLaunchKernelGGL(attn_kernel, dim3(1024), dim3(256), 0, stream,
                     Qp, Kp, Vp, mask, out);
}

// Round 5
// 515.518 us; speedup vs baseline: 1.3229x; 1.1122x over previous
//
#include <hip/hip_runtime.h>

typedef __attribute__((ext_vector_type(8))) short bf16x8;
typedef __attribute__((ext_vector_type(4))) float f32x4;
typedef __attribute__((ext_vector_type(2))) unsigned u32x2;

#define S_LEN 2048
#define NHEAD 16
#define DHEAD 64

__device__ __forceinline__ short f2bf(float f) {
  unsigned u = __builtin_bit_cast(unsigned, f);
  u += 0x7FFFu + ((u >> 16) & 1u);   // round-to-nearest-even
  return (short)(u >> 16);
}

// ---------------- projection: out[b,h,s,e] = sum_d in[b,s,h,d]*W[e,d] + bias[e]
__global__ __launch_bounds__(256) void proj_kernel(
    const float* __restrict__ qin, const float* __restrict__ kin,
    const float* __restrict__ vin,
    const float* __restrict__ Wq, const float* __restrict__ bq,
    const float* __restrict__ Wk, const float* __restrict__ bk,
    const float* __restrict__ Wv, const float* __restrict__ bv,
    short* __restrict__ Qp, short* __restrict__ Kp, short* __restrict__ Vp)
{
  const int wid = threadIdx.x >> 6;
  const int lane = threadIdx.x & 63;
  const int lr = lane & 15, lg = lane >> 4;
  const int gw = blockIdx.x * 4 + wid;      // 3072 waves total
  const int tensor = gw >> 10;              // 1024 waves per tensor (65536 rows / 64)
  const int rb0 = (gw & 1023) * 64;

  const float* in = tensor == 0 ? qin : (tensor == 1 ? kin : vin);
  const float* W  = tensor == 0 ? Wq  : (tensor == 1 ? Wk  : Wv);
  const float* bb = tensor == 0 ? bq  : (tensor == 1 ? bk  : bv);
  short* op       = tensor == 0 ? Qp  : (tensor == 1 ? Kp  : Vp);

  bf16x8 wf[4][2];
  #pragma unroll
  for (int et = 0; et < 4; ++et)
    #pragma unroll
    for (int h = 0; h < 2; ++h) {
      const float* s = &W[(et*16 + lr)*64 + h*32 + lg*8];
      bf16x8 t;
      #pragma unroll
      for (int e = 0; e < 8; ++e) t[e] = f2bf(s[e]);
      wf[et][h] = t;
    }
  float bias[4];
  #pragma unroll
  for (int et = 0; et < 4; ++et) bias[et] = bb[et*16 + lr];

  for (int blk = 0; blk < 4; ++blk) {
    const int rb = rb0 + blk*16;
    bf16x8 af[2];
    #pragma unroll
    for (int h = 0; h < 2; ++h) {
      const float* s = &in[(size_t)(rb + lr)*64 + h*32 + lg*8];
      bf16x8 t;
      #pragma unroll
      for (int e = 0; e < 8; ++e) t[e] = f2bf(s[e]);
      af[h] = t;
    }
    #pragma unroll
    for (int et = 0; et < 4; ++et) {
      f32x4 acc = {0.f, 0.f, 0.f, 0.f};
      acc = __builtin_amdgcn_mfma_f32_16x16x32_bf16(af[0], wf[et][0], acc, 0, 0, 0);
      acc = __builtin_amdgcn_mfma_f32_16x16x32_bf16(af[1], wf[et][1], acc, 0, 0, 0);
      #pragma unroll
      for (int r = 0; r < 4; ++r) {
        const int row = rb + lg*4 + r;        // flattened (b,s,h)
        const int hh = row & 15;
        const int ss = (row >> 4) & 2047;
        const int bi = row >> 15;
        const size_t orow = ((size_t)(bi*NHEAD + hh))*S_LEN + ss;
        op[orow*64 + et*16 + lr] = f2bf(acc[r] + bias[et]);
      }
    }
  }
}

// ---------------- threefry2x32-20, key (0,42), counter (0, idx), out = x0^x1
// keep <=> out < (7549747u<<9)  (exact integer form of u<0.9f)
#define TF_R2(r) \
  xa0 += xa1; xb0 += xb1; \
  xa1 = __builtin_amdgcn_alignbit(xa1, xa1, 32 - (r)) ^ xa0; \
  xb1 = __builtin_amdgcn_alignbit(xb1, xb1, 32 - (r)) ^ xb0;

#define TF_G2(r0, r1, r2, r3) TF_R2(r0) TF_R2(r1) TF_R2(r2) TF_R2(r3)

#define TF_K1 42u
#define TF_K2 (0x1BD11BDAu ^ 42u)
#define TF_THR 3865470464u   // 7549747u << 9

// full 20-round hash of (idx) and (idx+16); sets keep0, keep1
#define TF_HASH2(idx, keep0, keep1) { \
  unsigned xa0 = 0u, xa1 = (idx) + TF_K1; \
  unsigned xb0 = 0u, xb1 = (idx) + 16u + TF_K1; \
  TF_G2(13,15,26, 6)  xa0 += TF_K1; xa1 += TF_K2 + 1u;  xb0 += TF_K1; xb1 += TF_K2 + 1u; \
  TF_G2(17,29,16,24)  xa0 += TF_K2; xa1 += 2u;          xb0 += TF_K2; xb1 += 2u; \
  TF_G2(13,15,26, 6)                xa1 += TF_K1 + 3u;                xb1 += TF_K1 + 3u; \
  TF_G2(17,29,16,24)  xa0 += TF_K1; xa1 += TF_K2 + 4u;  xb0 += TF_K1; xb1 += TF_K2 + 4u; \
  TF_G2(13,15,26, 6)  xa0 += TF_K2; xa1 += 5u;          xb0 += TF_K2; xb1 += 5u; \
  keep0 = (xa0 ^ xa1) < TF_THR; \
  keep1 = (xb0 ^ xb1) < TF_THR; \
}

__device__ __forceinline__ unsigned pk_bf16(float lo, float hi) {
  unsigned r;
  asm("v_cvt_pk_bf16_f32 %0, %1, %2" : "=v"(r) : "v"(lo), "v"(hi));
  return r;
}

// ---------------- flash attention, swapped QK^T, in-register softmax
__global__ __launch_bounds__(256) void attn_kernel(
    const short* __restrict__ Qp, const short* __restrict__ Kp,
    const short* __restrict__ Vp, const float* __restrict__ mask,
    float* __restrict__ out)
{
  __shared__ short Kl[32][72];       // K tile, pad 64->72
  __shared__ short Vt[64][40];       // V tile transposed [d][k], pad 32->40
  __shared__ unsigned Pl[4][16][20]; // per-wave packed P' [q][k-pair dword], 80B rows

  const int wid = threadIdx.x >> 6;
  const int lane = threadIdx.x & 63;
  const int lr = lane & 15, lg = lane >> 4;
  const int qblk = blockIdx.x >> 5;
  const int bh = blockIdx.x & 31;
  const int b = bh >> 4;
  const int qbase = qblk*64 + wid*16;

  // Q fragments: lane holds Q[qbase+lr][h*32 + lg*8 + e]
  bf16x8 qf[2];
  #pragma unroll
  for (int h = 0; h < 2; ++h)
    qf[h] = *(const bf16x8*)&Qp[((size_t)bh*S_LEN + qbase + lr)*64 + h*32 + lg*8];

  f32x4 acc[4];
  #pragma unroll
  for (int dt = 0; dt < 4; ++dt) acc[dt] = (f32x4){0.f,0.f,0.f,0.f};
  float m_run = -1e30f;   // per-lane: q = qbase + lr
  float l_run = 0.f;

  const float* mrow_p = mask + (size_t)b*S_LEN*S_LEN + (size_t)(qbase + lr)*S_LEN;
  const unsigned rowbase = ((unsigned)(bh*S_LEN + qbase + lr)) << 11;

  const int tr = threadIdx.x >> 3;        // staging row 0..31
  const int tc = (threadIdx.x & 7) * 8;   // staging col base

  for (int kt = 0; kt < 64; ++kt) {
    const int kb = kt * 32;
    { // stage K tile and transposed V tile
      const size_t gbase = ((size_t)bh*S_LEN + kb + tr)*64 + tc;
      bf16x8 kv = *(const bf16x8*)&Kp[gbase];
      *(bf16x8*)&Kl[tr][tc] = kv;
      bf16x8 vv = *(const bf16x8*)&Vp[gbase];
      #pragma unroll
      for (int j = 0; j < 8; ++j) Vt[tc + j][tr] = vv[j];
    }
    __syncthreads();

    // mask: per-lane row, two 4-dword runs (k = kb + s2*16 + lg*4 + r)
    f32x4 mk0 = *(const f32x4*)(mrow_p + kb + lg*4);
    f32x4 mk1 = *(const f32x4*)(mrow_p + kb + 16 + lg*4);

    // dropout keep multipliers for this lane's 8 elements
    float km0[4], km1[4];
    #pragma unroll
    for (int r = 0; r < 4; ++r) {
      bool k0, k1;
      TF_HASH2(rowbase + (unsigned)(kb + lg*4 + r), k0, k1);
      km0[r] = k0 ? (1.0f/0.9f) : 0.0f;
      km1[r] = k1 ? (1.0f/0.9f) : 0.0f;
    }

    // swapped QK^T: sc[s2][r] = S[q=qbase+lr][kb + s2*16 + lg*4 + r]
    f32x4 sc0, sc1;
    {
      bf16x8 ka = *(const bf16x8*)&Kl[lr][lg*8];
      bf16x8 kb_ = *(const bf16x8*)&Kl[lr][32 + lg*8];
      f32x4 t = {0.f,0.f,0.f,0.f};
      t = __builtin_amdgcn_mfma_f32_16x16x32_bf16(ka, qf[0], t, 0, 0, 0);
      t = __builtin_amdgcn_mfma_f32_16x16x32_bf16(kb_, qf[1], t, 0, 0, 0);
      sc0 = t;
      bf16x8 kc = *(const bf16x8*)&Kl[16 + lr][lg*8];
      bf16x8 kd = *(const bf16x8*)&Kl[16 + lr][32 + lg*8];
      f32x4 u = {0.f,0.f,0.f,0.f};
      u = __builtin_amdgcn_mfma_f32_16x16x32_bf16(kc, qf[0], u, 0, 0, 0);
      u = __builtin_amdgcn_mfma_f32_16x16x32_bf16(kd, qf[1], u, 0, 0, 0);
      sc1 = u;
    }

    // in-register softmax over the lane's 8 values; row-reduce via 2 shfls
    float x0[4], x1[4];
    #pragma unroll
    for (int r = 0; r < 4; ++r) {
      x0[r] = sc0[r] * 0.125f + mk0[r];
      x1[r] = sc1[r] * 0.125f + mk1[r];
    }
    float tm = fmaxf(fmaxf(fmaxf(x0[0], x0[1]), fmaxf(x0[2], x0[3])),
                     fmaxf(fmaxf(x1[0], x1[1]), fmaxf(x1[2], x1[3])));
    tm = fmaxf(tm, __shfl_xor(tm, 16));
    tm = fmaxf(tm, __shfl_xor(tm, 32));
    const float mnew = fmaxf(m_run, tm);
    const float corr = __expf(m_run - mnew);
    m_run = mnew;
    float p0[4], p1[4];
    #pragma unroll
    for (int r = 0; r < 4; ++r) {
      p0[r] = __expf(x0[r] - mnew);
      p1[r] = __expf(x1[r] - mnew);
    }
    float rs = ((p0[0]+p0[1]) + (p0[2]+p0[3])) + ((p1[0]+p1[1]) + (p1[2]+p1[3]));
    rs += __shfl_xor(rs, 16);
    rs += __shfl_xor(rs, 32);
    l_run = l_run * corr + rs;

    // drop + pack P' into dwords (dword index = k>>1 = s2*8 + lg*2 + p)
    const unsigned w0 = pk_bf16(p0[0]*km0[0], p0[1]*km0[1]);
    const unsigned w1 = pk_bf16(p0[2]*km0[2], p0[3]*km0[3]);
    const unsigned w2 = pk_bf16(p1[0]*km1[0], p1[1]*km1[1]);
    const unsigned w3 = pk_bf16(p1[2]*km1[2], p1[3]*km1[3]);
    *(u32x2*)&Pl[wid][lr][lg*2]     = (u32x2){w0, w1};
    *(u32x2*)&Pl[wid][lr][8 + lg*2] = (u32x2){w2, w3};
    asm volatile("" ::: "memory");   // order Pl stores before Pl load (same wave)

    // rescale acc by corr of its own q-row (q = qbase + lg*4 + r)
    #pragma unroll
    for (int r = 0; r < 4; ++r) {
      const float c = __shfl(corr, lg*4 + r);
      #pragma unroll
      for (int dt = 0; dt < 4; ++dt) acc[dt][r] *= c;
    }

    // PV: A = P' from per-wave LDS, B = V via transposed tile
    bf16x8 pf = *(const bf16x8*)&Pl[wid][lr][lg*4];
    #pragma unroll
    for (int dt = 0; dt < 4; ++dt) {
      bf16x8 vf = *(const bf16x8*)&Vt[dt*16 + lr][lg*8];
      acc[dt] = __builtin_amdgcn_mfma_f32_16x16x32_bf16(pf, vf, acc[dt], 0, 0, 0);
    }
    __syncthreads();   // before next-iter staging overwrites Kl/Vt
  }

  #pragma unroll
  for (int r = 0; r < 4; ++r) {
    const int qrow = qbase + lg*4 + r;
    const float linv = 1.0f / __shfl(l_run, lg*4 + r);
    #pragma unroll
    for (int dt = 0; dt < 4; ++dt)
      out[((size_t)bh*S_LEN + qrow)*64 + dt*16 + lr] = acc[dt][r] * linv;
  }
}

extern "C" void kernel_launch(void* const* d_in, const int* in_sizes, int n_in,
                              void* d_out, int out_size, void* d_ws, size_t ws_size,
                              hipStream_t stream) {
  const float* qin  = (const float*)d_in[0];
  const float* kin  = (const float*)d_in[1];
  const float* vin  = (const float*)d_in[2];
  const float* mask = (const float*)d_in[3];
  const float* Wq = (const float*)d_in[4];
  const float* bq = (const float*)d_in[5];
  const float* Wk = (const float*)d_in[6];
  const float* bk = (const float*)d_in[7];
  const float* Wv = (const float*)d_in[8];
  const float* bv = (const float*)d_in[9];
  float* out = (float*)d_out;

  // ws layout: Qp/Kp/Vp bf16 [32][2048][64] (8 MiB each)
  short* Qp = (short*)d_ws;
  short* Kp = Qp + 4194304;
  short* Vp = Kp + 4194304;

  hipLaunchKernelGGL(proj_kernel, dim3(768), dim3(256), 0, stream,
                     qin, kin, vin, Wq, bq, Wk, bk, Wv, bv, Qp, Kp, Vp);
  hipLaunchKernelGGL(attn_kernel, dim3(1024), dim3(256), 0, stream,
                     Qp, Kp, Vp, mask, out);
}

// Round 7
// 481.211 us; speedup vs baseline: 1.4172x; 1.0713x over previous
//
#include <hip/hip_runtime.h>

typedef __attribute__((ext_vector_type(8))) short bf16x8;
typedef __attribute__((ext_vector_type(4))) float f32x4;
typedef __attribute__((ext_vector_type(2))) unsigned u32x2;

#define S_LEN 2048
#define NHEAD 16
#define DHEAD 64

__device__ __forceinline__ short f2bf(float f) {
  unsigned u = __builtin_bit_cast(unsigned, f);
  u += 0x7FFFu + ((u >> 16) & 1u);   // round-to-nearest-even
  return (short)(u >> 16);
}

// ---------------- projection: out[b,h,s,e] = sum_d in[b,s,h,d]*W[e,d] + bias[e]
__global__ __launch_bounds__(256) void proj_kernel(
    const float* __restrict__ qin, const float* __restrict__ kin,
    const float* __restrict__ vin,
    const float* __restrict__ Wq, const float* __restrict__ bq,
    const float* __restrict__ Wk, const float* __restrict__ bk,
    const float* __restrict__ Wv, const float* __restrict__ bv,
    short* __restrict__ Qp, short* __restrict__ Kp, short* __restrict__ Vp)
{
  const int wid = threadIdx.x >> 6;
  const int lane = threadIdx.x & 63;
  const int lr = lane & 15, lg = lane >> 4;
  const int gw = blockIdx.x * 4 + wid;      // 3072 waves total
  const int tensor = gw >> 10;              // 1024 waves per tensor (65536 rows / 64)
  const int rb0 = (gw & 1023) * 64;

  const float* in = tensor == 0 ? qin : (tensor == 1 ? kin : vin);
  const float* W  = tensor == 0 ? Wq  : (tensor == 1 ? Wk  : Wv);
  const float* bb = tensor == 0 ? bq  : (tensor == 1 ? bk  : bv);
  short* op       = tensor == 0 ? Qp  : (tensor == 1 ? Kp  : Vp);

  bf16x8 wf[4][2];
  #pragma unroll
  for (int et = 0; et < 4; ++et)
    #pragma unroll
    for (int h = 0; h < 2; ++h) {
      const float* s = &W[(et*16 + lr)*64 + h*32 + lg*8];
      bf16x8 t;
      #pragma unroll
      for (int e = 0; e < 8; ++e) t[e] = f2bf(s[e]);
      wf[et][h] = t;
    }
  float bias[4];
  #pragma unroll
  for (int et = 0; et < 4; ++et) bias[et] = bb[et*16 + lr];

  for (int blk = 0; blk < 4; ++blk) {
    const int rb = rb0 + blk*16;
    bf16x8 af[2];
    #pragma unroll
    for (int h = 0; h < 2; ++h) {
      const float* s = &in[(size_t)(rb + lr)*64 + h*32 + lg*8];
      bf16x8 t;
      #pragma unroll
      for (int e = 0; e < 8; ++e) t[e] = f2bf(s[e]);
      af[h] = t;
    }
    #pragma unroll
    for (int et = 0; et < 4; ++et) {
      f32x4 acc = {0.f, 0.f, 0.f, 0.f};
      acc = __builtin_amdgcn_mfma_f32_16x16x32_bf16(af[0], wf[et][0], acc, 0, 0, 0);
      acc = __builtin_amdgcn_mfma_f32_16x16x32_bf16(af[1], wf[et][1], acc, 0, 0, 0);
      #pragma unroll
      for (int r = 0; r < 4; ++r) {
        const int row = rb + lg*4 + r;        // flattened (b,s,h)
        const int hh = row & 15;
        const int ss = (row >> 4) & 2047;
        const int bi = row >> 15;
        const size_t orow = ((size_t)(bi*NHEAD + hh))*S_LEN + ss;
        op[orow*64 + et*16 + lr] = f2bf(acc[r] + bias[et]);
      }
    }
  }
}

// ---------------- threefry2x32-20, key (0,42), counter (0, idx), out = x0^x1
// keep <=> out < (7549747u<<9)  (exact integer form of u<0.9f)
#define TF_R2(r) \
  xa0 += xa1; xb0 += xb1; \
  xa1 = __builtin_amdgcn_alignbit(xa1, xa1, 32 - (r)) ^ xa0; \
  xb1 = __builtin_amdgcn_alignbit(xb1, xb1, 32 - (r)) ^ xb0;

#define TF_G2(r0, r1, r2, r3) TF_R2(r0) TF_R2(r1) TF_R2(r2) TF_R2(r3)

#define TF_K1 42u
#define TF_K2 (0x1BD11BDAu ^ 42u)
#define TF_THR 3865470464u   // 7549747u << 9

// full 20-round hash of (idx) and (idx+16); sets keep0, keep1
#define TF_HASH2(idx, keep0, keep1) { \
  unsigned xa0 = 0u, xa1 = (idx) + TF_K1; \
  unsigned xb0 = 0u, xb1 = (idx) + 16u + TF_K1; \
  TF_G2(13,15,26, 6)  xa0 += TF_K1; xa1 += TF_K2 + 1u;  xb0 += TF_K1; xb1 += TF_K2 + 1u; \
  TF_G2(17,29,16,24)  xa0 += TF_K2; xa1 += 2u;          xb0 += TF_K2; xb1 += 2u; \
  TF_G2(13,15,26, 6)                xa1 += TF_K1 + 3u;                xb1 += TF_K1 + 3u; \
  TF_G2(17,29,16,24)  xa0 += TF_K1; xa1 += TF_K2 + 4u;  xb0 += TF_K1; xb1 += TF_K2 + 4u; \
  TF_G2(13,15,26, 6)  xa0 += TF_K2; xa1 += 5u;          xb0 += TF_K2; xb1 += 5u; \
  keep0 = (xa0 ^ xa1) < TF_THR; \
  keep1 = (xb0 ^ xb1) < TF_THR; \
}

__device__ __forceinline__ unsigned pk_bf16(float lo, float hi) {
  unsigned r;
  asm("v_cvt_pk_bf16_f32 %0, %1, %2" : "=v"(r) : "v"(lo), "v"(hi));
  return r;
}

// ---------------- flash attention, swapped QK^T, in-register softmax
// Vt holds V transposed [d][k] with k-block XOR swizzle:
//   element (d,k) stored at Vt[d][k ^ (8*((d>>3)&3))]  (write 2-way/free,
//   read b128 stays aligned+contiguous; both sides swizzled — rule #21)
__global__ __launch_bounds__(256) void attn_kernel(
    const short* __restrict__ Qp, const short* __restrict__ Kp,
    const short* __restrict__ Vp, const float* __restrict__ mask,
    float* __restrict__ out)
{
  __shared__ short Kl[32][72];       // K tile, pad 64->72
  __shared__ short Vt[64][40];       // V tile transposed [d][k^swz], pad 32->40
  __shared__ unsigned Pl[4][16][20]; // per-wave packed P' [q][k-pair dword], 80B rows

  const int wid = threadIdx.x >> 6;
  const int lane = threadIdx.x & 63;
  const int lr = lane & 15, lg = lane >> 4;
  const int qblk = blockIdx.x >> 5;
  const int bh = blockIdx.x & 31;
  const int b = bh >> 4;
  const int qbase = qblk*64 + wid*16;

  // Q fragments: lane holds Q[qbase+lr][h*32 + lg*8 + e]
  bf16x8 qf[2];
  #pragma unroll
  for (int h = 0; h < 2; ++h)
    qf[h] = *(const bf16x8*)&Qp[((size_t)bh*S_LEN + qbase + lr)*64 + h*32 + lg*8];

  f32x4 acc[4];
  #pragma unroll
  for (int dt = 0; dt < 4; ++dt) acc[dt] = (f32x4){0.f,0.f,0.f,0.f};
  float m_run = -1e30f;   // per-lane: q = qbase + lr
  float l_run = 0.f;

  const float* mrow_p = mask + (size_t)b*S_LEN*S_LEN + (size_t)(qbase + lr)*S_LEN;
  const unsigned rowbase = ((unsigned)(bh*S_LEN + qbase + lr)) << 11;

  const int tr = threadIdx.x >> 3;        // staging row 0..31
  const int tc = (threadIdx.x & 7) * 8;   // staging col base
  const int vswz = tr ^ (8*((tc >> 3) & 3));   // swizzled k-column for V writes
  const short* kvbase = &Kp[((size_t)bh*S_LEN + tr)*64 + tc];
  const short* vvbase = &Vp[((size_t)bh*S_LEN + tr)*64 + tc];

  // prologue: prefetch kt=0 K/V rows into registers
  bf16x8 kv = *(const bf16x8*)(kvbase);
  bf16x8 vv = *(const bf16x8*)(vvbase);

  for (int kt = 0; kt < 64; ++kt) {
    const int kb = kt * 32;
    // stage K tile and swizzle-transposed V tile from prefetch regs
    *(bf16x8*)&Kl[tr][tc] = kv;
    #pragma unroll
    for (int j = 0; j < 8; ++j) Vt[tc + j][vswz] = vv[j];
    __syncthreads();

    // prefetch next tile (clamped on last iter; wave-uniform select)
    {
      const int kbn = (kt < 63) ? (kb + 32) : kb;
      kv = *(const bf16x8*)(kvbase + (size_t)kbn*64);
      vv = *(const bf16x8*)(vvbase + (size_t)kbn*64);
    }

    // mask: per-lane row, two 4-dword runs (k = kb + s2*16 + lg*4 + r)
    f32x4 mk0 = *(const f32x4*)(mrow_p + kb + lg*4);
    f32x4 mk1 = *(const f32x4*)(mrow_p + kb + 16 + lg*4);

    // dropout keep multipliers for this lane's 8 elements
    float km0[4], km1[4];
    #pragma unroll
    for (int r = 0; r < 4; ++r) {
      bool k0, k1;
      TF_HASH2(rowbase + (unsigned)(kb + lg*4 + r), k0, k1);
      km0[r] = k0 ? (1.0f/0.9f) : 0.0f;
      km1[r] = k1 ? (1.0f/0.9f) : 0.0f;
    }

    // swapped QK^T: sc[s2][r] = S[q=qbase+lr][kb + s2*16 + lg*4 + r]
    f32x4 sc0, sc1;
    {
      bf16x8 ka = *(const bf16x8*)&Kl[lr][lg*8];
      bf16x8 kb_ = *(const bf16x8*)&Kl[lr][32 + lg*8];
      f32x4 t = {0.f,0.f,0.f,0.f};
      t = __builtin_amdgcn_mfma_f32_16x16x32_bf16(ka, qf[0], t, 0, 0, 0);
      t = __builtin_amdgcn_mfma_f32_16x16x32_bf16(kb_, qf[1], t, 0, 0, 0);
      sc0 = t;
      bf16x8 kc = *(const bf16x8*)&Kl[16 + lr][lg*8];
      bf16x8 kd = *(const bf16x8*)&Kl[16 + lr][32 + lg*8];
      f32x4 u = {0.f,0.f,0.f,0.f};
      u = __builtin_amdgcn_mfma_f32_16x16x32_bf16(kc, qf[0], u, 0, 0, 0);
      u = __builtin_amdgcn_mfma_f32_16x16x32_bf16(kd, qf[1], u, 0, 0, 0);
      sc1 = u;
    }

    // in-register softmax over the lane's 8 values; row-reduce via 2 shfls
    float x0[4], x1[4];
    #pragma unroll
    for (int r = 0; r < 4; ++r) {
      x0[r] = sc0[r] * 0.125f + mk0[r];
      x1[r] = sc1[r] * 0.125f + mk1[r];
    }
    float tm = fmaxf(fmaxf(fmaxf(x0[0], x0[1]), fmaxf(x0[2], x0[3])),
                     fmaxf(fmaxf(x1[0], x1[1]), fmaxf(x1[2], x1[3])));
    tm = fmaxf(tm, __shfl_xor(tm, 16));
    tm = fmaxf(tm, __shfl_xor(tm, 32));
    const float mnew = fmaxf(m_run, tm);
    const float corr = __expf(m_run - mnew);
    m_run = mnew;
    float p0[4], p1[4];
    #pragma unroll
    for (int r = 0; r < 4; ++r) {
      p0[r] = __expf(x0[r] - mnew);
      p1[r] = __expf(x1[r] - mnew);
    }
    float rs = ((p0[0]+p0[1]) + (p0[2]+p0[3])) + ((p1[0]+p1[1]) + (p1[2]+p1[3]));
    rs += __shfl_xor(rs, 16);
    rs += __shfl_xor(rs, 32);
    l_run = l_run * corr + rs;

    // drop + pack P' into dwords (dword index = k>>1 = s2*8 + lg*2 + p)
    const unsigned w0 = pk_bf16(p0[0]*km0[0], p0[1]*km0[1]);
    const unsigned w1 = pk_bf16(p0[2]*km0[2], p0[3]*km0[3]);
    const unsigned w2 = pk_bf16(p1[0]*km1[0], p1[1]*km1[1]);
    const unsigned w3 = pk_bf16(p1[2]*km1[2], p1[3]*km1[3]);
    *(u32x2*)&Pl[wid][lr][lg*2]     = (u32x2){w0, w1};
    *(u32x2*)&Pl[wid][lr][8 + lg*2] = (u32x2){w2, w3};
    asm volatile("" ::: "memory");   // order Pl stores before Pl load (same wave)

    // rescale acc by corr of its own q-row (q = qbase + lg*4 + r)
    #pragma unroll
    for (int r = 0; r < 4; ++r) {
      const float c = __shfl(corr, lg*4 + r);
      #pragma unroll
      for (int dt = 0; dt < 4; ++dt) acc[dt][r] *= c;
    }

    // PV: A = P' from per-wave LDS, B = V via swizzled transposed tile
    bf16x8 pf = *(const bf16x8*)&Pl[wid][lr][lg*4];
    #pragma unroll
    for (int dt = 0; dt < 4; ++dt) {
      const int vc = (lg ^ ((dt*2 + (lr >> 3)) & 3)) * 8;
      bf16x8 vf = *(const bf16x8*)&Vt[dt*16 + lr][vc];
      acc[dt] = __builtin_amdgcn_mfma_f32_16x16x32_bf16(pf, vf, acc[dt], 0, 0, 0);
    }
    __syncthreads();   // before next-iter staging overwrites Kl/Vt
  }

  #pragma unroll
  for (int r = 0; r < 4; ++r) {
    const int qrow = qbase + lg*4 + r;
    const float linv = 1.0f / __shfl(l_run, lg*4 + r);
    #pragma unroll
    for (int dt = 0; dt < 4; ++dt)
      out[((size_t)bh*S_LEN + qrow)*64 + dt*16 + lr] = acc[dt][r] * linv;
  }
}

extern "C" void kernel_launch(void* const* d_in, const int* in_sizes, int n_in,
                              void* d_out, int out_size, void* d_ws, size_t ws_size,
                              hipStream_t stream) {
  const float* qin  = (const float*)d_in[0];
  const float* kin  = (const float*)d_in[1];
  const float* vin  = (const float*)d_in[2];
  const float* mask = (const float*)d_in[3];
  const float* Wq = (const float*)d_in[4];
  const float* bq = (const float*)d_in[5];
  const float* Wk = (const float*)d_in[6];
  const float* bk = (const float*)d_in[7];
  const float* Wv = (const float*)d_in[8];
  const float* bv = (const float*)d_in[9];
  float* out = (float*)d_out;

  // ws layout: Qp/Kp/Vp bf16 [32][2048][64] (8 MiB each)
  short* Qp = (short*)d_ws;
  short* Kp = Qp + 4194304;
  short* Vp = Kp + 4194304;

  hipLaunchKernelGGL(proj_kernel, dim3(768), dim3(256), 0, stream,
                     qin, kin, vin, Wq, bq, Wk, bk, Wv, bv, Qp, Kp, Vp);
  hipLaunchKernelGGL(attn_kernel, dim3(1024), dim3(256), 0, stream,
                     Qp, Kp, Vp, mask, out);
}

// Round 11
// 427.761 us; speedup vs baseline: 1.5943x; 1.1250x over previous
//
#include <hip/hip_runtime.h>

typedef __attribute__((ext_vector_type(8))) short bf16x8;
typedef __attribute__((ext_vector_type(4))) float f32x4;
typedef __attribute__((ext_vector_type(2))) unsigned u32x2;

#define S_LEN 2048
#define NHEAD 16
#define DHEAD 64

__device__ __forceinline__ short f2bf(float f) {
  unsigned u = __builtin_bit_cast(unsigned, f);
  u += 0x7FFFu + ((u >> 16) & 1u);   // round-to-nearest-even
  return (short)(u >> 16);
}

// ---------------- projection: out[b,h,s,e] = sum_d in[b,s,h,d]*W[e,d] + bias[e]
__global__ __launch_bounds__(256) void proj_kernel(
    const float* __restrict__ qin, const float* __restrict__ kin,
    const float* __restrict__ vin,
    const float* __restrict__ Wq, const float* __restrict__ bq,
    const float* __restrict__ Wk, const float* __restrict__ bk,
    const float* __restrict__ Wv, const float* __restrict__ bv,
    short* __restrict__ Qp, short* __restrict__ Kp, short* __restrict__ Vp)
{
  const int wid = threadIdx.x >> 6;
  const int lane = threadIdx.x & 63;
  const int lr = lane & 15, lg = lane >> 4;
  const int gw = blockIdx.x * 4 + wid;      // 3072 waves total
  const int tensor = gw >> 10;              // 1024 waves per tensor (65536 rows / 64)
  const int rb0 = (gw & 1023) * 64;

  const float* in = tensor == 0 ? qin : (tensor == 1 ? kin : vin);
  const float* W  = tensor == 0 ? Wq  : (tensor == 1 ? Wk  : Wv);
  const float* bb = tensor == 0 ? bq  : (tensor == 1 ? bk  : bv);
  short* op       = tensor == 0 ? Qp  : (tensor == 1 ? Kp  : Vp);

  bf16x8 wf[4][2];
  #pragma unroll
  for (int et = 0; et < 4; ++et)
    #pragma unroll
    for (int h = 0; h < 2; ++h) {
      const float* s = &W[(et*16 + lr)*64 + h*32 + lg*8];
      bf16x8 t;
      #pragma unroll
      for (int e = 0; e < 8; ++e) t[e] = f2bf(s[e]);
      wf[et][h] = t;
    }
  float bias[4];
  #pragma unroll
  for (int et = 0; et < 4; ++et) bias[et] = bb[et*16 + lr];

  for (int blk = 0; blk < 4; ++blk) {
    const int rb = rb0 + blk*16;
    bf16x8 af[2];
    #pragma unroll
    for (int h = 0; h < 2; ++h) {
      const float* s = &in[(size_t)(rb + lr)*64 + h*32 + lg*8];
      bf16x8 t;
      #pragma unroll
      for (int e = 0; e < 8; ++e) t[e] = f2bf(s[e]);
      af[h] = t;
    }
    #pragma unroll
    for (int et = 0; et < 4; ++et) {
      f32x4 acc = {0.f, 0.f, 0.f, 0.f};
      acc = __builtin_amdgcn_mfma_f32_16x16x32_bf16(af[0], wf[et][0], acc, 0, 0, 0);
      acc = __builtin_amdgcn_mfma_f32_16x16x32_bf16(af[1], wf[et][1], acc, 0, 0, 0);
      #pragma unroll
      for (int r = 0; r < 4; ++r) {
        const int row = rb + lg*4 + r;        // flattened (b,s,h)
        const int hh = row & 15;
        const int ss = (row >> 4) & 2047;
        const int bi = row >> 15;
        const size_t orow = ((size_t)(bi*NHEAD + hh))*S_LEN + ss;
        op[orow*64 + et*16 + lr] = f2bf(acc[r] + bias[et]);
      }
    }
  }
}

// ---------------- threefry2x32-20, key (0,42), counter (0, idx), out = x0^x1
// keep <=> out < (7549747u<<9)  (exact integer form of u<0.9f)
#define TF_R2(r) \
  xa0 += xa1; xb0 += xb1; \
  xa1 = __builtin_amdgcn_alignbit(xa1, xa1, 32 - (r)) ^ xa0; \
  xb1 = __builtin_amdgcn_alignbit(xb1, xb1, 32 - (r)) ^ xb0;

#define TF_G2(r0, r1, r2, r3) TF_R2(r0) TF_R2(r1) TF_R2(r2) TF_R2(r3)

#define TF_K1 42u
#define TF_K2 (0x1BD11BDAu ^ 42u)
#define TF_THR 3865470464u   // 7549747u << 9

// full 20-round hash of (idx) and (idx+16); sets keep0, keep1
#define TF_HASH2(idx, keep0, keep1) { \
  unsigned xa0 = 0u, xa1 = (idx) + TF_K1; \
  unsigned xb0 = 0u, xb1 = (idx) + 16u + TF_K1; \
  TF_G2(13,15,26, 6)  xa0 += TF_K1; xa1 += TF_K2 + 1u;  xb0 += TF_K1; xb1 += TF_K2 + 1u; \
  TF_G2(17,29,16,24)  xa0 += TF_K2; xa1 += 2u;          xb0 += TF_K2; xb1 += 2u; \
  TF_G2(13,15,26, 6)                xa1 += TF_K1 + 3u;                xb1 += TF_K1 + 3u; \
  TF_G2(17,29,16,24)  xa0 += TF_K1; xa1 += TF_K2 + 4u;  xb0 += TF_K1; xb1 += TF_K2 + 4u; \
  TF_G2(13,15,26, 6)  xa0 += TF_K2; xa1 += 5u;          xb0 += TF_K2; xb1 += 5u; \
  keep0 = (xa0 ^ xa1) < TF_THR; \
  keep1 = (xb0 ^ xb1) < TF_THR; \
}

__device__ __forceinline__ unsigned pk_bf16(float lo, float hi) {
  unsigned r;
  asm("v_cvt_pk_bf16_f32 %0, %1, %2" : "=v"(r) : "v"(lo), "v"(hi));
  return r;
}

// ---------------- flash attention, swapped QK^T, in-register softmax
// Double-buffered K/V tiles, ONE barrier per kt.
// Vt swizzle: element (d,k) at Vt[d][k ^ (8*((d>>3)&3))] (write+read both swizzled)
__global__ __launch_bounds__(256, 4) void attn_kernel(
    const short* __restrict__ Qp, const short* __restrict__ Kp,
    const short* __restrict__ Vp, const float* __restrict__ mask,
    float* __restrict__ out)
{
  __shared__ short Kl[2][32][72];      // K tiles, pad 64->72
  __shared__ short Vt[2][64][40];      // V tiles transposed [d][k^swz], pad 32->40
  __shared__ unsigned Pl[4][16][20];   // per-wave packed P' [q][k-pair dword]

  const int wid = threadIdx.x >> 6;
  const int lane = threadIdx.x & 63;
  const int lr = lane & 15, lg = lane >> 4;
  const int qblk = blockIdx.x >> 5;
  const int bh = blockIdx.x & 31;
  const int b = bh >> 4;
  const int qbase = qblk*64 + wid*16;

  // Q fragments: lane holds Q[qbase+lr][h*32 + lg*8 + e]
  bf16x8 qf[2];
  #pragma unroll
  for (int h = 0; h < 2; ++h)
    qf[h] = *(const bf16x8*)&Qp[((size_t)bh*S_LEN + qbase + lr)*64 + h*32 + lg*8];

  f32x4 acc[4];
  #pragma unroll
  for (int dt = 0; dt < 4; ++dt) acc[dt] = (f32x4){0.f,0.f,0.f,0.f};
  float m_run = -1e30f;   // per-lane: q = qbase + lr
  float l_run = 0.f;

  const float* mrow_p = mask + (size_t)b*S_LEN*S_LEN + (size_t)(qbase + lr)*S_LEN;
  const unsigned rowbase = ((unsigned)(bh*S_LEN + qbase + lr)) << 11;

  const int tr = threadIdx.x >> 3;        // staging row 0..31
  const int tc = (threadIdx.x & 7) * 8;   // staging col base
  const int vswz = tr ^ (8*((tc >> 3) & 3));   // swizzled k-column for V writes
  const short* kvbase = &Kp[((size_t)bh*S_LEN + tr)*64 + tc];
  const short* vvbase = &Vp[((size_t)bh*S_LEN + tr)*64 + tc];

  // prologue: stage tile 0 into buf0, prefetch tile 1 into regs
  bf16x8 kv = *(const bf16x8*)(kvbase);
  bf16x8 vv = *(const bf16x8*)(vvbase);
  *(bf16x8*)&Kl[0][tr][tc] = kv;
  #pragma unroll
  for (int j = 0; j < 8; ++j) Vt[0][tc + j][vswz] = vv[j];
  kv = *(const bf16x8*)(kvbase + 32*64);
  vv = *(const bf16x8*)(vvbase + 32*64);
  __syncthreads();

  #pragma unroll 2
  for (int kt = 0; kt < 64; ++kt) {
    const int cur = kt & 1, nxt = cur ^ 1;
    const int kb = kt * 32;

    // stage tile kt+1 into the other buffer (regs prefetched last iter)
    *(bf16x8*)&Kl[nxt][tr][tc] = kv;
    #pragma unroll
    for (int j = 0; j < 8; ++j) Vt[nxt][tc + j][vswz] = vv[j];

    // prefetch tile kt+2 (clamped; last-iter staging is dead but safe)
    const int kbn = (kt < 62) ? (kb + 64) : 2016;
    kv = *(const bf16x8*)(kvbase + (size_t)kbn*64);
    vv = *(const bf16x8*)(vvbase + (size_t)kbn*64);

    // mask: per-lane row, two 4-dword runs (k = kb + s2*16 + lg*4 + r)
    f32x4 mk0 = *(const f32x4*)(mrow_p + kb + lg*4);
    f32x4 mk1 = *(const f32x4*)(mrow_p + kb + 16 + lg*4);

    // dropout keep multipliers for this lane's 8 elements
    float km0[4], km1[4];
    #pragma unroll
    for (int r = 0; r < 4; ++r) {
      bool k0, k1;
      TF_HASH2(rowbase + (unsigned)(kb + lg*4 + r), k0, k1);
      km0[r] = k0 ? (1.0f/0.9f) : 0.0f;
      km1[r] = k1 ? (1.0f/0.9f) : 0.0f;
    }

    // swapped QK^T: sc[s2][r] = S[q=qbase+lr][kb + s2*16 + lg*4 + r]
    f32x4 sc0, sc1;
    {
      bf16x8 ka = *(const bf16x8*)&Kl[cur][lr][lg*8];
      bf16x8 kb_ = *(const bf16x8*)&Kl[cur][lr][32 + lg*8];
      f32x4 t = {0.f,0.f,0.f,0.f};
      t = __builtin_amdgcn_mfma_f32_16x16x32_bf16(ka, qf[0], t, 0, 0, 0);
      t = __builtin_amdgcn_mfma_f32_16x16x32_bf16(kb_, qf[1], t, 0, 0, 0);
      sc0 = t;
      bf16x8 kc = *(const bf16x8*)&Kl[cur][16 + lr][lg*8];
      bf16x8 kd = *(const bf16x8*)&Kl[cur][16 + lr][32 + lg*8];
      f32x4 u = {0.f,0.f,0.f,0.f};
      u = __builtin_amdgcn_mfma_f32_16x16x32_bf16(kc, qf[0], u, 0, 0, 0);
      u = __builtin_amdgcn_mfma_f32_16x16x32_bf16(kd, qf[1], u, 0, 0, 0);
      sc1 = u;
    }

    // in-register softmax over the lane's 8 values; row-reduce via 2 shfls
    float x0[4], x1[4];
    #pragma unroll
    for (int r = 0; r < 4; ++r) {
      x0[r] = sc0[r] * 0.125f + mk0[r];
      x1[r] = sc1[r] * 0.125f + mk1[r];
    }
    float tm = fmaxf(fmaxf(fmaxf(x0[0], x0[1]), fmaxf(x0[2], x0[3])),
                     fmaxf(fmaxf(x1[0], x1[1]), fmaxf(x1[2], x1[3])));
    tm = fmaxf(tm, __shfl_xor(tm, 16));
    tm = fmaxf(tm, __shfl_xor(tm, 32));
    const float mnew = fmaxf(m_run, tm);
    const float corr = __expf(m_run - mnew);
    m_run = mnew;
    float p0[4], p1[4];
    #pragma unroll
    for (int r = 0; r < 4; ++r) {
      p0[r] = __expf(x0[r] - mnew);
      p1[r] = __expf(x1[r] - mnew);
    }
    float rs = ((p0[0]+p0[1]) + (p0[2]+p0[3])) + ((p1[0]+p1[1]) + (p1[2]+p1[3]));
    rs += __shfl_xor(rs, 16);
    rs += __shfl_xor(rs, 32);
    l_run = l_run * corr + rs;

    // drop + pack P' into dwords (dword index = k>>1 = s2*8 + lg*2 + p)
    const unsigned w0 = pk_bf16(p0[0]*km0[0], p0[1]*km0[1]);
    const unsigned w1 = pk_bf16(p0[2]*km0[2], p0[3]*km0[3]);
    const unsigned w2 = pk_bf16(p1[0]*km1[0], p1[1]*km1[1]);
    const unsigned w3 = pk_bf16(p1[2]*km1[2], p1[3]*km1[3]);
    *(u32x2*)&Pl[wid][lr][lg*2]     = (u32x2){w0, w1};
    *(u32x2*)&Pl[wid][lr][8 + lg*2] = (u32x2){w2, w3};
    asm volatile("" ::: "memory");   // order Pl stores before Pl load (same wave)

    // rescale acc by corr of its own q-row (q = qbase + lg*4 + r)
    #pragma unroll
    for (int r = 0; r < 4; ++r) {
      const float c = __shfl(corr, lg*4 + r);
      #pragma unroll
      for (int dt = 0; dt < 4; ++dt) acc[dt][r] *= c;
    }

    // PV: A = P' from per-wave LDS, B = V via swizzled transposed tile
    bf16x8 pf = *(const bf16x8*)&Pl[wid][lr][lg*4];
    #pragma unroll
    for (int dt = 0; dt < 4; ++dt) {
      const int vc = (lg ^ ((dt*2 + (lr >> 3)) & 3)) * 8;
      bf16x8 vf = *(const bf16x8*)&Vt[cur][dt*16 + lr][vc];
      acc[dt] = __builtin_amdgcn_mfma_f32_16x16x32_bf16(pf, vf, acc[dt], 0, 0, 0);
    }
    __syncthreads();   // single barrier per kt: next tile staged, reads done
  }

  #pragma unroll
  for (int r = 0; r < 4; ++r) {
    const int qrow = qbase + lg*4 + r;
    const float linv = 1.0f / __shfl(l_run, lg*4 + r);
    #pragma unroll
    for (int dt = 0; dt < 4; ++dt)
      out[((size_t)bh*S_LEN + qrow)*64 + dt*16 + lr] = acc[dt][r] * linv;
  }
}

extern "C" void kernel_launch(void* const* d_in, const int* in_sizes, int n_in,
                              void* d_out, int out_size, void* d_ws, size_t ws_size,
                              hipStream_t stream) {
  const float* qin  = (const float*)d_in[0];
  const float* kin  = (const float*)d_in[1];
  const float* vin  = (const float*)d_in[2];
  const float* mask = (const float*)d_in[3];
  const float* Wq = (const float*)d_in[4];
  const float* bq = (const float*)d_in[5];
  const float* Wk = (const float*)d_in[6];
  const float* bk = (const float*)d_in[7];
  const float* Wv = (const float*)d_in[8];
  const float* bv = (const float*)d_in[9];
  float* out = (float*)d_out;

  // ws layout: Qp/Kp/Vp bf16 [32][2048][64] (8 MiB each)
  short* Qp = (short*)d_ws;
  short* Kp = Qp + 4194304;
  short* Vp = Kp + 4194304;

  hipLaunchKernelGGL(proj_kernel, dim3(768), dim3(256), 0, stream,
                     qin, kin, vin, Wq, bq, Wk, bk, Wv, bv, Qp, Kp, Vp);
  hipLaunchKernelGGL(attn_kernel, dim3(1024), dim3(256), 0, stream,
                     Qp, Kp, Vp, mask, out);
}